// Round 16
// baseline (28.057 us; speedup 1.0000x reference)
//
#include <hip/hip_runtime.h>

#define NQ 11

// One wave per sample; 2048-amplitude real statevector in 16 float2 VGPR
// pairs per lane.  Amplitude index i (wire w <-> bit (10-w) of i):
//   i = (k<<7) | (comp<<6) | lane
//   wires 0..3  -> k bits 3..0    (packed float2 register butterflies)
//   wire  4     -> comp           (within-float2 butterfly)
//   wires 5..10 -> lane bits 5..0 (cross-lane butterflies)
// CZ gates folded into the NEXT RY's coefficients (verified r3/r5/r6/r9).
//
// Cross-lane mask 32/16: v_permlane{32,16}_swap_b32 (doc semantics:
// vdst_hi <-> vsrc_lo  /  vdst odd-16-rows <-> vsrc even-16-rows), inline
// asm PADDED with s_nop 1 on both sides (hazard wait-states — the leading
// suspect for r12's probe-pass/dense-fail corruption).  A BITWISE
// verification probe runs the full RY5/RY6 pair-gates on synthetic data
// through the padded-permlane path AND a shfl-emulated reference with
// identical arithmetic; only if both match exactly does the main loop use
// permlane.  Mismatch -> verified r9 batched-shfl fallback (zero risk).
// Masks 8,4,2,1 -> DPP (verified r5/r6/r9).

typedef float f32x2 __attribute__((ext_vector_type(2)));

template <int N> struct IC { static constexpr int value = N; };

__device__ __forceinline__ f32x2 b2(float s) { f32x2 r; r.x = s; r.y = s; return r; }
__device__ __forceinline__ f32x2 fma2(f32x2 a, f32x2 b, f32x2 c) {
    return __builtin_elementwise_fma(a, b, c);
}

// Padded swaps: s_nop both sides, fused in one asm blob (atomic unit).
__device__ __forceinline__ void pswap32(float& a, float& b) {
    asm volatile("s_nop 1\n\tv_permlane32_swap_b32 %0, %1\n\ts_nop 1"
                 : "+v"(a), "+v"(b));
}
__device__ __forceinline__ void pswap16(float& a, float& b) {
    asm volatile("s_nop 1\n\tv_permlane16_swap_b32 %0, %1\n\ts_nop 1"
                 : "+v"(a), "+v"(b));
}

template <int CTRL>
__device__ __forceinline__ float dpp_mov(float x) {
    const int xi = __builtin_bit_cast(int, x);
    return __builtin_bit_cast(float,
        __builtin_amdgcn_update_dpp(xi, xi, CTRL, 0xf, 0xf, false));
}
#define DPP_XOR1 0xB1   // quad_perm [1,0,3,2]
#define DPP_XOR2 0x4E   // quad_perm [2,3,0,1]
#define DPP_XOR3 0x1B   // quad_perm [3,2,1,0]
#define DPP_XOR7 0x141  // row_half_mirror
#define DPP_XOR8 0x128  // row_ror:8 (xor-8 within 16-lane row)

__device__ __forceinline__ unsigned fbits(float v) {
    return __builtin_bit_cast(unsigned, v);
}

// Packed butterfly on k-bit KB; preceding CZ sign: -1 iff (k0 & KSB).
#define RY_K_F(KB, KSB, C, S)                                                \
    _Pragma("unroll")                                                        \
    for (int g = 0; g < 8; ++g) {                                            \
        const int k0 = ((g >> (KB)) << ((KB) + 1)) | (g & ((1 << (KB)) - 1));\
        const int k1 = k0 | (1 << (KB));                                     \
        const f32x2 a_ = v2[k0], b_ = v2[k1];                                \
        const f32x2 Cv = b2(C), Sv = b2(S);                                  \
        if (k0 & (KSB)) {                                                    \
            v2[k0] = fma2(Cv, a_, Sv * b_);                                  \
            v2[k1] = fma2(Sv, a_, -(Cv * b_));                               \
        } else {                                                             \
            v2[k0] = fma2(Cv, a_, -(Sv * b_));                               \
            v2[k1] = fma2(Sv, a_, Cv * b_);                                  \
        }                                                                    \
    }

// DS shuffle gate, BATCHED (verified r9 fallback path).
#define RY_DS_B(SHFL, CV, SV)                                                \
    {                                                                        \
        f32x2 pa_[16];                                                       \
        _Pragma("unroll")                                                    \
        for (int k = 0; k < 16; ++k) {                                       \
            pa_[k].x = SHFL(v2[k].x);                                        \
            pa_[k].y = SHFL(v2[k].y);                                        \
        }                                                                    \
        _Pragma("unroll")                                                    \
        for (int k = 0; k < 16; ++k)                                         \
            v2[k] = fma2(CV, v2[k], (SV) * pa_[k]);                          \
    }

// DPP lane gate (VALU pipe, short latency).
#define RY_DPP(PGETX, CV, SV)                                                \
    _Pragma("unroll")                                                        \
    for (int k = 0; k < 16; ++k) {                                           \
        f32x2 pa_;                                                           \
        pa_.x = PGETX(v2[k].x);                                              \
        pa_.y = PGETX(v2[k].y);                                              \
        v2[k] = fma2(CV, v2[k], (SV) * pa_);                                 \
    }

__global__ __launch_bounds__(256, 2) void qru_kernel(
    const float* __restrict__ x,   // [2048, 16]
    const float* __restrict__ w,   // [11]
    float* __restrict__ out)       // [2048, 11]
{
    const int lane = threadIdx.x & 63;
    const int n    = blockIdx.x * 4 + (threadIdx.x >> 6);

    // ---- BITWISE gate-verification probe (dense-context, hazard-exercising)
    const bool hi5  = (lane & 32) != 0;
    const bool hi4  = (lane & 16) != 0;
    bool ok32, ok16;
    {
        // synthetic data + synthetic c=0.6, s=0.8 with real sign structure
        const float xs = (float)lane + 1.0f;
        const float ys = 3.0f * (float)lane + 100.0f;
        const float SSc = hi5 ?  0.8f : -0.8f;   // RY5-form cross coeff
        const float CMc = hi5 ? -0.6f :  0.6f;   // RY5-form own coeff
        // shfl-emulated D-semantics reference (identical arithmetic):
        const float sxp = __shfl_xor(xs, 32), syp = __shfl_xor(ys, 32);
        const float d_ref = hi5 ? syp : xs;
        const float e_ref = hi5 ? ys  : sxp;
        const float t0r = __builtin_fmaf(SSc, e_ref, 0.6f * d_ref);
        const float t1r = __builtin_fmaf(CMc, e_ref, 0.8f * d_ref);
        const float t0rs = __shfl_xor(t0r, 32), t1rs = __shfl_xor(t1r, 32);
        const float xr = hi5 ? t1rs : t0r;
        const float yr = hi5 ? t1r  : t0rs;
        // padded-permlane path, same arithmetic:
        float d = xs, e = ys;
        pswap32(d, e);
        float t0 = __builtin_fmaf(SSc, e, 0.6f * d);
        float t1 = __builtin_fmaf(CMc, e, 0.8f * d);
        pswap32(t0, t1);
        ok32 = __all((fbits(t0) == fbits(xr)) && (fbits(t1) == fbits(yr))) != 0;
    }
    {
        const float xs = 2.0f * (float)lane + 5.0f;
        const float ys = 7.0f * (float)lane + 300.0f;
        const float SSc = hi5 ?  0.8f : -0.8f;   // RY6 sigma by lane bit5
        const float CMc = hi5 ? -0.6f :  0.6f;
        const float sxp = __shfl_xor(xs, 16), syp = __shfl_xor(ys, 16);
        const float d_ref = hi4 ? syp : xs;
        const float e_ref = hi4 ? ys  : sxp;
        const float t0r = __builtin_fmaf(SSc, e_ref, 0.6f * d_ref);
        const float t1r = __builtin_fmaf(CMc, e_ref, 0.8f * d_ref);
        const float t0rs = __shfl_xor(t0r, 16), t1rs = __shfl_xor(t1r, 16);
        const float xr = hi4 ? t1rs : t0r;
        const float yr = hi4 ? t1r  : t0rs;
        float d = xs, e = ys;
        pswap16(d, e);
        float t0 = __builtin_fmaf(SSc, e, 0.6f * d);
        float t1 = __builtin_fmaf(CMc, e, 0.8f * d);
        pswap16(t0, t1);
        ok16 = __all((fbits(t0) == fbits(xr)) && (fbits(t1) == fbits(yr))) != 0;
    }
    const int mode = (ok32 && ok16) ? 1 : 0;

    // ---- input angles (vectorized) + half-angle sin/cos ----
    const float4 xa = *(const float4*)(x + n * 16);
    const float4 xb = *(const float4*)(x + n * 16 + 4);
    const float4 xc = *(const float4*)(x + n * 16 + 8);
    const float xv[NQ] = {xa.x, xa.y, xa.z, xa.w, xb.x, xb.y, xb.z, xb.w,
                          xc.x, xc.y, xc.z};
    float ci[NQ], si[NQ];
#pragma unroll
    for (int q = 0; q < NQ; ++q) {
        const float h = xv[q] * 0.5f;
        si[q] = __sinf(h); ci[q] = __cosf(h);
    }
    float cw[NQ], sw[NQ];
#pragma unroll
    for (int q = 0; q < NQ; ++q) {
        const float h = w[q] * 0.5f;
        sw[q] = __sinf(h); cw[q] = __cosf(h);
    }

    // ---- initial product state ----
    const float laneF =
        ((lane & 32) ? si[5]  : ci[5])  *
        ((lane & 16) ? si[6]  : ci[6])  *
        ((lane & 8)  ? si[7]  : ci[7])  *
        ((lane & 4)  ? si[8]  : ci[8])  *
        ((lane & 2)  ? si[9]  : ci[9])  *
        ((lane & 1)  ? si[10] : ci[10]);

    f32x2 v2[16];
#pragma unroll
    for (int k = 0; k < 16; ++k) {
        const float base = laneF * ((k & 8) ? si[0] : ci[0])
                                 * ((k & 4) ? si[1] : ci[1])
                                 * ((k & 2) ? si[2] : ci[2])
                                 * ((k & 1) ? si[3] : ci[3]);
        v2[k].x = base * ci[4];
        v2[k].y = base * si[4];
    }

    // ---- folded per-lane coefficient constants (verified r3/r5/r6/r9) ----
    const float X0m = (lane & 1) ?  sw[0] : -sw[0];
    const float Y0m = (lane & 1) ? -cw[0] :  cw[0];
    // RY5: pair-frame coeffs (sigma = -1 iff pair-comp==1, i.e. lane>=32
    // after swap32); identical constants serve the fallback partner-fetch
    // frame (comp0 cross / comp1 own), as verified in r9.
    const float SS5 = hi5 ?  sw[5] : -sw[5];
    const float C5m = hi5 ? -cw[5] :  cw[5];
    f32x2 Cv5; Cv5.x = cw[5]; Cv5.y = C5m;
    f32x2 Sv5; Sv5.x = SS5;   Sv5.y = sw[5];
    // RY6: pair-frame coeffs (sigma by amplitude lane-bit5, swap16-invariant)
    const float S6x = hi5 ?  sw[6] : -sw[6];
    const float C6x = hi5 ? -cw[6] :  cw[6];
    // fallback partner-fetch frame for RY6:
    const f32x2 C6v  = b2(((lane & 48) == 48) ? -cw[6]  : cw[6]);
    const f32x2 S6v  = b2((lane & 48) ? sw[6]  : -sw[6]);
    // DPP gates: own=(both)? -C:C ; cross=(either)? +S:-S
    const f32x2 C7v  = b2(((lane & 24) == 24) ? -cw[7]  : cw[7]);
    const f32x2 S7v  = b2((lane & 24) ? sw[7]  : -sw[7]);
    const f32x2 C8v  = b2(((lane & 12) == 12) ? -cw[8]  : cw[8]);
    const f32x2 S8v  = b2((lane & 12) ? sw[8]  : -sw[8]);
    const f32x2 C9v  = b2(((lane & 6)  == 6)  ? -cw[9]  : cw[9]);
    const f32x2 S9v  = b2((lane & 6)  ? sw[9]  : -sw[9]);
    const f32x2 C10v = b2(((lane & 3)  == 3)  ? -cw[10] : cw[10]);
    const f32x2 S10v = b2((lane & 3)  ? sw[10] : -sw[10]);

    // RY4 (comp butterfly), incoming CZ(3,4): sigma1 = -1 iff k odd.
    f32x2 C4p; C4p.x = cw[4];  C4p.y =  cw[4];
    f32x2 S4p; S4p.x = -sw[4]; S4p.y =  sw[4];
    f32x2 C4m; C4m.x = cw[4];  C4m.y = -cw[4];
    f32x2 S4m; S4m.x = sw[4];  S4m.y =  sw[4];

    auto shfl32 = [](float t) { return __shfl_xor(t, 32); };
    auto shfl16 = [](float t) { return __shfl_xor(t, 16); };
    auto dppx8  = [](float t) { return dpp_mov<DPP_XOR8>(t); };
    auto dppx4  = [](float t) { return dpp_mov<DPP_XOR3>(dpp_mov<DPP_XOR7>(t)); };
    auto dppx2  = [](float t) { return dpp_mov<DPP_XOR2>(t); };
    auto dppx1  = [](float t) { return dpp_mov<DPP_XOR1>(t); };

    auto run = [&](auto mc) {
        constexpr bool PL = (decltype(mc)::value == 1);

        auto layer = [&](float X0, float Y0) {
            // RY0 on k bit 3 (incoming CZ folded into X0/Y0)
            {
                const f32x2 c0 = b2(cw[0]), s0 = b2(sw[0]);
                const f32x2 x0 = b2(X0),    y0 = b2(Y0);
#pragma unroll
                for (int k = 0; k < 8; ++k) {
                    const f32x2 a_ = v2[k], b_ = v2[k | 8];
                    v2[k]     = fma2(c0, a_, x0 * b_);
                    v2[k | 8] = fma2(s0, a_, y0 * b_);
                }
            }
            RY_K_F(2, 8, cw[1], sw[1])      // RY1, fold CZ(0,1)
            RY_K_F(1, 4, cw[2], sw[2])      // RY2, fold CZ(1,2)
            RY_K_F(0, 2, cw[3], sw[3])      // RY3, fold CZ(2,3)

            // RY4 (component), fold CZ(3,4) (k bit0)
#pragma unroll
            for (int k = 0; k < 16; ++k) {
                const f32x2 s_ = __builtin_shufflevector(v2[k], v2[k], 1, 0);
                v2[k] = (k & 1) ? fma2(C4m, v2[k], S4m * s_)
                                : fma2(C4p, v2[k], S4p * s_);
            }

            if constexpr (PL) {
                // RY5 (lane bit5): permlane32 pair trick (probe-verified)
#pragma unroll
                for (int k = 0; k < 16; ++k) {
                    float d = v2[k].x, e = v2[k].y;
                    pswap32(d, e);          // d=u0, e=u1 per pair
                    float t0 = __builtin_fmaf(SS5, e, cw[5] * d);
                    float t1 = __builtin_fmaf(C5m, e, sw[5] * d);
                    pswap32(t0, t1);
                    v2[k].x = t0; v2[k].y = t1;
                }
                // RY6 (lane bit4): permlane16 pair trick
#pragma unroll
                for (int k = 0; k < 16; ++k) {
                    float d = v2[k].x, e = v2[k].y;
                    pswap16(d, e);
                    float t0 = __builtin_fmaf(S6x, e, cw[6] * d);
                    float t1 = __builtin_fmaf(C6x, e, sw[6] * d);
                    pswap16(t0, t1);
                    v2[k].x = t0; v2[k].y = t1;
                }
            } else {
                RY_DS_B(shfl32, Cv5, Sv5)   // RY5 — DS batched (verified r9)
                RY_DS_B(shfl16, C6v, S6v)   // RY6 — DS batched
            }

            RY_DPP(dppx8,  C7v,  S7v)       // RY7,  fold CZ(6,7)  — DPP
            RY_DPP(dppx4,  C8v,  S8v)       // RY8,  fold CZ(7,8)  — DPP x2
            RY_DPP(dppx2,  C9v,  S9v)       // RY9,  fold CZ(8,9)  — DPP
            RY_DPP(dppx1,  C10v, S10v)      // RY10, fold CZ(9,10) — DPP
            // CZ(10,0) -> folded into next layer's RY0; pure sign after last.
        };

        layer(-sw[0], cw[0]);               // layer 0: RY0 has no incoming CZ
#pragma unroll 1
        for (int l = 1; l < 6; ++l) layer(X0m, Y0m);
    };

    if (mode == 1) run(IC<1>{});
    else           run(IC<0>{});

    // ---- measurement: out[w] = sum_i amp_i^2 * (1 - 2*bit_w(i)) ----
    f32x2 T = b2(0.f), A3 = b2(0.f), A2 = b2(0.f), A1 = b2(0.f), A0 = b2(0.f);
#pragma unroll
    for (int k = 0; k < 16; ++k) {
        const f32x2 p = v2[k] * v2[k];
        T = T + p;
        if (k & 8) A3 = A3 + p;
        if (k & 4) A2 = A2 + p;
        if (k & 2) A1 = A1 + p;
        if (k & 1) A0 = A0 + p;
    }
    const float tot = T.x + T.y;

    float q[NQ];
    q[0] = tot - 2.f * (A3.x + A3.y);
    q[1] = tot - 2.f * (A2.x + A2.y);
    q[2] = tot - 2.f * (A1.x + A1.y);
    q[3] = tot - 2.f * (A0.x + A0.y);
    q[4] = tot - 2.f * T.y;
    q[5]  = (lane & 32) ? -tot : tot;
    q[6]  = (lane & 16) ? -tot : tot;
    q[7]  = (lane & 8)  ? -tot : tot;
    q[8]  = (lane & 4)  ? -tot : tot;
    q[9]  = (lane & 2)  ? -tot : tot;
    q[10] = (lane & 1)  ? -tot : tot;

    // epilogue wave reduction (verified r9)
#pragma unroll
    for (int wq = 0; wq < NQ; ++wq) q[wq] += __shfl_xor(q[wq], 32);
#pragma unroll
    for (int wq = 0; wq < NQ; ++wq) q[wq] += __shfl_xor(q[wq], 16);
#pragma unroll
    for (int wq = 0; wq < NQ; ++wq) q[wq] += dpp_mov<DPP_XOR8>(q[wq]);
#pragma unroll
    for (int wq = 0; wq < NQ; ++wq)
        q[wq] += dpp_mov<DPP_XOR3>(dpp_mov<DPP_XOR7>(q[wq]));
#pragma unroll
    for (int wq = 0; wq < NQ; ++wq) q[wq] += dpp_mov<DPP_XOR2>(q[wq]);
#pragma unroll
    for (int wq = 0; wq < NQ; ++wq) q[wq] += dpp_mov<DPP_XOR1>(q[wq]);

    if (lane == 0) {
#pragma unroll
        for (int wq = 0; wq < NQ; ++wq) out[n * 11 + wq] = q[wq];
    }
}

extern "C" void kernel_launch(void* const* d_in, const int* in_sizes, int n_in,
                              void* d_out, int out_size, void* d_ws, size_t ws_size,
                              hipStream_t stream) {
    const float* x = (const float*)d_in[0];   // [8,256,16] f32
    const float* w = (const float*)d_in[1];   // [11] f32
    float* out = (float*)d_out;               // [8,256,11] f32

    qru_kernel<<<512, 256, 0, stream>>>(x, w, out);
}

// Round 17
// 25.196 us; speedup vs baseline: 1.1136x; 1.1136x over previous
//
#include <hip/hip_runtime.h>

#define NQ 11

// One wave per sample; 2048-amplitude real statevector in 16 float2 VGPR
// pairs per lane.  Amplitude index i (wire w <-> bit (10-w) of i):
//   i = (k<<7) | (comp<<6) | lane
//   wires 0..3  -> k bits 3..0    (packed float2 register butterflies)
//   wire  4     -> comp           (within-float2 butterfly)
//   wires 5..10 -> lane bits 5..0 (cross-lane butterflies)
// CZ gates folded into the NEXT RY's coefficients (verified r3/r5/r6/r9).
//
// Cross-lane mask 32/16: v_permlane{32,16}_swap_b32, D-semantics
// (vdst_hi <-> vsrc_lo / vdst odd-16-rows <-> vsrc even-rows) — r16 PROVED
// correctness end-to-end with s_nop padding (hazard wait-states were r12's
// corruption), but padding cost more than it saved.  r17: NO nops; hazard
// distance comes from BATCHING (16 independent swaps -> 32 FMAs -> 16
// back-swaps; dependent pairs >=16 instrs apart).  A worst-case-adjacency
// bitwise probe (VALU-write -> 3x swap -> VALU-read, single asm blob, vs
// shfl-emulated D reference with identical arithmetic) gates the path:
// pass -> batched no-nop permlane; fail -> verified r9 shfl fallback.
// Masks 8,4,2,1 -> DPP (verified r5/r6/r9).

typedef float f32x2 __attribute__((ext_vector_type(2)));

template <int N> struct IC { static constexpr int value = N; };

__device__ __forceinline__ f32x2 b2(float s) { f32x2 r; r.x = s; r.y = s; return r; }
__device__ __forceinline__ f32x2 fma2(f32x2 a, f32x2 b, f32x2 c) {
    return __builtin_elementwise_fma(a, b, c);
}
__device__ __forceinline__ unsigned fbits(float v) {
    return __builtin_bit_cast(unsigned, v);
}

// Bare swaps — no padding; batching provides hazard distance.
__device__ __forceinline__ void pswap32(float& a, float& b) {
    asm volatile("v_permlane32_swap_b32 %0, %1" : "+v"(a), "+v"(b));
}
__device__ __forceinline__ void pswap16(float& a, float& b) {
    asm volatile("v_permlane16_swap_b32 %0, %1" : "+v"(a), "+v"(b));
}

template <int CTRL>
__device__ __forceinline__ float dpp_mov(float x) {
    const int xi = __builtin_bit_cast(int, x);
    return __builtin_bit_cast(float,
        __builtin_amdgcn_update_dpp(xi, xi, CTRL, 0xf, 0xf, false));
}
#define DPP_XOR1 0xB1   // quad_perm [1,0,3,2]
#define DPP_XOR2 0x4E   // quad_perm [2,3,0,1]
#define DPP_XOR3 0x1B   // quad_perm [3,2,1,0]
#define DPP_XOR7 0x141  // row_half_mirror
#define DPP_XOR8 0x128  // row_ror:8 (xor-8 within 16-lane row)

// Worst-case-adjacency probes: VALU write -> swap -> swap -> swap -> VALU
// read, all back-to-back inside one asm blob (cannot be folded/reordered).
// Triple swap == net single swap; also exercises permlane->permlane
// same-register adjacency.  Bitwise-compared vs shfl-emulated D semantics.
__device__ __forceinline__ bool probe32(int lane) {
    const float xa = (float)(lane + 1);
    const float xb = (float)(3 * lane + 100);
    float a, b;
    asm volatile(
        "v_mul_f32 %0, 2.0, %2\n\t"
        "v_mul_f32 %1, 4.0, %3\n\t"
        "v_permlane32_swap_b32 %0, %1\n\t"
        "v_permlane32_swap_b32 %0, %1\n\t"
        "v_permlane32_swap_b32 %0, %1\n\t"
        "v_add_f32 %0, %0, %1"
        : "=&v"(a), "=&v"(b)
        : "v"(xa), "v"(xb));
    const float A = 2.0f * xa, B = 4.0f * xb;
    const bool lo = (lane & 32) == 0;
    const float Ap = __shfl_xor(A, 32), Bp = __shfl_xor(B, 32);
    const float ar = lo ? A : Bp;    // a' = lo ? a : b[l-32]
    const float br = lo ? Ap : B;    // b' = lo ? a[l+32] : b
    return __all((fbits(a) == fbits(ar + br)) && (fbits(b) == fbits(br))) != 0;
}
__device__ __forceinline__ bool probe16(int lane) {
    const float xa = (float)(2 * lane + 5);
    const float xb = (float)(7 * lane + 300);
    float a, b;
    asm volatile(
        "v_mul_f32 %0, 2.0, %2\n\t"
        "v_mul_f32 %1, 4.0, %3\n\t"
        "v_permlane16_swap_b32 %0, %1\n\t"
        "v_permlane16_swap_b32 %0, %1\n\t"
        "v_permlane16_swap_b32 %0, %1\n\t"
        "v_add_f32 %0, %0, %1"
        : "=&v"(a), "=&v"(b)
        : "v"(xa), "v"(xb));
    const float A = 2.0f * xa, B = 4.0f * xb;
    const bool lo = (lane & 16) == 0;
    const float Ap = __shfl_xor(A, 16), Bp = __shfl_xor(B, 16);
    const float ar = lo ? A : Bp;    // a' = lo16 ? a : b[l-16]
    const float br = lo ? Ap : B;    // b' = lo16 ? a[l+16] : b
    return __all((fbits(a) == fbits(ar + br)) && (fbits(b) == fbits(br))) != 0;
}

// Packed butterfly on k-bit KB; preceding CZ sign: -1 iff (k0 & KSB).
#define RY_K_F(KB, KSB, C, S)                                                \
    _Pragma("unroll")                                                        \
    for (int g = 0; g < 8; ++g) {                                            \
        const int k0 = ((g >> (KB)) << ((KB) + 1)) | (g & ((1 << (KB)) - 1));\
        const int k1 = k0 | (1 << (KB));                                     \
        const f32x2 a_ = v2[k0], b_ = v2[k1];                                \
        const f32x2 Cv = b2(C), Sv = b2(S);                                  \
        if (k0 & (KSB)) {                                                    \
            v2[k0] = fma2(Cv, a_, Sv * b_);                                  \
            v2[k1] = fma2(Sv, a_, -(Cv * b_));                               \
        } else {                                                             \
            v2[k0] = fma2(Cv, a_, -(Sv * b_));                               \
            v2[k1] = fma2(Sv, a_, Cv * b_);                                  \
        }                                                                    \
    }

// DS shuffle gate, BATCHED (verified r9 fallback path).
#define RY_DS_B(SHFL, CV, SV)                                                \
    {                                                                        \
        f32x2 pa_[16];                                                       \
        _Pragma("unroll")                                                    \
        for (int k = 0; k < 16; ++k) {                                       \
            pa_[k].x = SHFL(v2[k].x);                                        \
            pa_[k].y = SHFL(v2[k].y);                                        \
        }                                                                    \
        _Pragma("unroll")                                                    \
        for (int k = 0; k < 16; ++k)                                         \
            v2[k] = fma2(CV, v2[k], (SV) * pa_[k]);                          \
    }

// Batched permlane pair gate: 16 swaps -> 32 FMAs -> 16 back-swaps.
// SWAPF in {pswap32,pswap16}; Ccross/Cown are the swapped-frame u1 coeffs.
#define RY_PL_B(SWAPF, CW, SW, SX, CX)                                       \
    {                                                                        \
        float d_[16], e_[16];                                                \
        _Pragma("unroll")                                                    \
        for (int k = 0; k < 16; ++k) { d_[k] = v2[k].x; e_[k] = v2[k].y; }   \
        _Pragma("unroll")                                                    \
        for (int k = 0; k < 16; ++k) SWAPF(d_[k], e_[k]);                    \
        _Pragma("unroll")                                                    \
        for (int k = 0; k < 16; ++k) {                                       \
            const float t0 = __builtin_fmaf((SX), e_[k], (CW) * d_[k]);      \
            const float t1 = __builtin_fmaf((CX), e_[k], (SW) * d_[k]);      \
            d_[k] = t0; e_[k] = t1;                                          \
        }                                                                    \
        _Pragma("unroll")                                                    \
        for (int k = 0; k < 16; ++k) SWAPF(d_[k], e_[k]);                    \
        _Pragma("unroll")                                                    \
        for (int k = 0; k < 16; ++k) { v2[k].x = d_[k]; v2[k].y = e_[k]; }   \
    }

// DPP lane gate (VALU pipe, short latency).
#define RY_DPP(PGETX, CV, SV)                                                \
    _Pragma("unroll")                                                        \
    for (int k = 0; k < 16; ++k) {                                           \
        f32x2 pa_;                                                           \
        pa_.x = PGETX(v2[k].x);                                              \
        pa_.y = PGETX(v2[k].y);                                              \
        v2[k] = fma2(CV, v2[k], (SV) * pa_);                                 \
    }

__global__ __launch_bounds__(256, 2) void qru_kernel(
    const float* __restrict__ x,   // [2048, 16]
    const float* __restrict__ w,   // [11]
    float* __restrict__ out)       // [2048, 11]
{
    const int lane = threadIdx.x & 63;
    const int n    = blockIdx.x * 4 + (threadIdx.x >> 6);

    const int mode = (probe32(lane) && probe16(lane)) ? 1 : 0;

    // ---- input angles (vectorized) + half-angle sin/cos ----
    const float4 xa = *(const float4*)(x + n * 16);
    const float4 xb = *(const float4*)(x + n * 16 + 4);
    const float4 xc = *(const float4*)(x + n * 16 + 8);
    const float xv[NQ] = {xa.x, xa.y, xa.z, xa.w, xb.x, xb.y, xb.z, xb.w,
                          xc.x, xc.y, xc.z};
    float ci[NQ], si[NQ];
#pragma unroll
    for (int q = 0; q < NQ; ++q) {
        const float h = xv[q] * 0.5f;
        si[q] = __sinf(h); ci[q] = __cosf(h);
    }
    float cw[NQ], sw[NQ];
#pragma unroll
    for (int q = 0; q < NQ; ++q) {
        const float h = w[q] * 0.5f;
        sw[q] = __sinf(h); cw[q] = __cosf(h);
    }

    // ---- initial product state ----
    const float laneF =
        ((lane & 32) ? si[5]  : ci[5])  *
        ((lane & 16) ? si[6]  : ci[6])  *
        ((lane & 8)  ? si[7]  : ci[7])  *
        ((lane & 4)  ? si[8]  : ci[8])  *
        ((lane & 2)  ? si[9]  : ci[9])  *
        ((lane & 1)  ? si[10] : ci[10]);

    f32x2 v2[16];
#pragma unroll
    for (int k = 0; k < 16; ++k) {
        const float base = laneF * ((k & 8) ? si[0] : ci[0])
                                 * ((k & 4) ? si[1] : ci[1])
                                 * ((k & 2) ? si[2] : ci[2])
                                 * ((k & 1) ? si[3] : ci[3]);
        v2[k].x = base * ci[4];
        v2[k].y = base * si[4];
    }

    // ---- folded per-lane coefficient constants (verified r3/r5/r6/r9/r16) ----
    const bool hi5 = (lane & 32) != 0;
    const float X0m = (lane & 1) ?  sw[0] : -sw[0];
    const float Y0m = (lane & 1) ? -cw[0] :  cw[0];
    // RY5 swapped-frame u1 coeffs (sigma = -1 iff comp==1; comp==bit5 there);
    // the same constants serve the fallback partner-fetch frame (r9).
    const float SS5 = hi5 ?  sw[5] : -sw[5];
    const float C5m = hi5 ? -cw[5] :  cw[5];
    f32x2 Cv5; Cv5.x = cw[5]; Cv5.y = C5m;
    f32x2 Sv5; Sv5.x = SS5;   Sv5.y = sw[5];
    // RY6 swapped-frame u1 coeffs (sigma by amp lane-bit5, swap16-invariant)
    const float S6x = hi5 ?  sw[6] : -sw[6];
    const float C6x = hi5 ? -cw[6] :  cw[6];
    // fallback partner-fetch frame for RY6:
    const f32x2 C6v  = b2(((lane & 48) == 48) ? -cw[6]  : cw[6]);
    const f32x2 S6v  = b2((lane & 48) ? sw[6]  : -sw[6]);
    // DPP gates: own=(both)? -C:C ; cross=(either)? +S:-S
    const f32x2 C7v  = b2(((lane & 24) == 24) ? -cw[7]  : cw[7]);
    const f32x2 S7v  = b2((lane & 24) ? sw[7]  : -sw[7]);
    const f32x2 C8v  = b2(((lane & 12) == 12) ? -cw[8]  : cw[8]);
    const f32x2 S8v  = b2((lane & 12) ? sw[8]  : -sw[8]);
    const f32x2 C9v  = b2(((lane & 6)  == 6)  ? -cw[9]  : cw[9]);
    const f32x2 S9v  = b2((lane & 6)  ? sw[9]  : -sw[9]);
    const f32x2 C10v = b2(((lane & 3)  == 3)  ? -cw[10] : cw[10]);
    const f32x2 S10v = b2((lane & 3)  ? sw[10] : -sw[10]);

    // RY4 (comp butterfly), incoming CZ(3,4): sigma1 = -1 iff k odd.
    f32x2 C4p; C4p.x = cw[4];  C4p.y =  cw[4];
    f32x2 S4p; S4p.x = -sw[4]; S4p.y =  sw[4];
    f32x2 C4m; C4m.x = cw[4];  C4m.y = -cw[4];
    f32x2 S4m; S4m.x = sw[4];  S4m.y =  sw[4];

    auto shfl32 = [](float t) { return __shfl_xor(t, 32); };
    auto shfl16 = [](float t) { return __shfl_xor(t, 16); };
    auto dppx8  = [](float t) { return dpp_mov<DPP_XOR8>(t); };
    auto dppx4  = [](float t) { return dpp_mov<DPP_XOR3>(dpp_mov<DPP_XOR7>(t)); };
    auto dppx2  = [](float t) { return dpp_mov<DPP_XOR2>(t); };
    auto dppx1  = [](float t) { return dpp_mov<DPP_XOR1>(t); };

    auto run = [&](auto mc) {
        constexpr bool PL = (decltype(mc)::value == 1);

        auto layer = [&](float X0, float Y0) {
            // RY0 on k bit 3 (incoming CZ folded into X0/Y0)
            {
                const f32x2 c0 = b2(cw[0]), s0 = b2(sw[0]);
                const f32x2 x0 = b2(X0),    y0 = b2(Y0);
#pragma unroll
                for (int k = 0; k < 8; ++k) {
                    const f32x2 a_ = v2[k], b_ = v2[k | 8];
                    v2[k]     = fma2(c0, a_, x0 * b_);
                    v2[k | 8] = fma2(s0, a_, y0 * b_);
                }
            }
            RY_K_F(2, 8, cw[1], sw[1])      // RY1, fold CZ(0,1)
            RY_K_F(1, 4, cw[2], sw[2])      // RY2, fold CZ(1,2)
            RY_K_F(0, 2, cw[3], sw[3])      // RY3, fold CZ(2,3)

            // RY4 (component), fold CZ(3,4) (k bit0)
#pragma unroll
            for (int k = 0; k < 16; ++k) {
                const f32x2 s_ = __builtin_shufflevector(v2[k], v2[k], 1, 0);
                v2[k] = (k & 1) ? fma2(C4m, v2[k], S4m * s_)
                                : fma2(C4p, v2[k], S4p * s_);
            }

            if constexpr (PL) {
                RY_PL_B(pswap32, cw[5], sw[5], SS5, C5m)  // RY5, fold CZ(4,5)
                RY_PL_B(pswap16, cw[6], sw[6], S6x, C6x)  // RY6, fold CZ(5,6)
            } else {
                RY_DS_B(shfl32, Cv5, Sv5)   // RY5 — DS batched (verified r9)
                RY_DS_B(shfl16, C6v, S6v)   // RY6 — DS batched
            }

            RY_DPP(dppx8,  C7v,  S7v)       // RY7,  fold CZ(6,7)  — DPP
            RY_DPP(dppx4,  C8v,  S8v)       // RY8,  fold CZ(7,8)  — DPP x2
            RY_DPP(dppx2,  C9v,  S9v)       // RY9,  fold CZ(8,9)  — DPP
            RY_DPP(dppx1,  C10v, S10v)      // RY10, fold CZ(9,10) — DPP
            // CZ(10,0) -> folded into next layer's RY0; pure sign after last.
        };

        layer(-sw[0], cw[0]);               // layer 0: RY0 has no incoming CZ
#pragma unroll 1
        for (int l = 1; l < 6; ++l) layer(X0m, Y0m);
    };

    if (mode == 1) run(IC<1>{});
    else           run(IC<0>{});

    // ---- measurement: out[w] = sum_i amp_i^2 * (1 - 2*bit_w(i)) ----
    f32x2 T = b2(0.f), A3 = b2(0.f), A2 = b2(0.f), A1 = b2(0.f), A0 = b2(0.f);
#pragma unroll
    for (int k = 0; k < 16; ++k) {
        const f32x2 p = v2[k] * v2[k];
        T = T + p;
        if (k & 8) A3 = A3 + p;
        if (k & 4) A2 = A2 + p;
        if (k & 2) A1 = A1 + p;
        if (k & 1) A0 = A0 + p;
    }
    const float tot = T.x + T.y;

    float q[NQ];
    q[0] = tot - 2.f * (A3.x + A3.y);
    q[1] = tot - 2.f * (A2.x + A2.y);
    q[2] = tot - 2.f * (A1.x + A1.y);
    q[3] = tot - 2.f * (A0.x + A0.y);
    q[4] = tot - 2.f * T.y;
    q[5]  = (lane & 32) ? -tot : tot;
    q[6]  = (lane & 16) ? -tot : tot;
    q[7]  = (lane & 8)  ? -tot : tot;
    q[8]  = (lane & 4)  ? -tot : tot;
    q[9]  = (lane & 2)  ? -tot : tot;
    q[10] = (lane & 1)  ? -tot : tot;

    // epilogue wave reduction (verified r9)
#pragma unroll
    for (int wq = 0; wq < NQ; ++wq) q[wq] += __shfl_xor(q[wq], 32);
#pragma unroll
    for (int wq = 0; wq < NQ; ++wq) q[wq] += __shfl_xor(q[wq], 16);
#pragma unroll
    for (int wq = 0; wq < NQ; ++wq) q[wq] += dpp_mov<DPP_XOR8>(q[wq]);
#pragma unroll
    for (int wq = 0; wq < NQ; ++wq)
        q[wq] += dpp_mov<DPP_XOR3>(dpp_mov<DPP_XOR7>(q[wq]));
#pragma unroll
    for (int wq = 0; wq < NQ; ++wq) q[wq] += dpp_mov<DPP_XOR2>(q[wq]);
#pragma unroll
    for (int wq = 0; wq < NQ; ++wq) q[wq] += dpp_mov<DPP_XOR1>(q[wq]);

    if (lane == 0) {
#pragma unroll
        for (int wq = 0; wq < NQ; ++wq) out[n * 11 + wq] = q[wq];
    }
}

extern "C" void kernel_launch(void* const* d_in, const int* in_sizes, int n_in,
                              void* d_out, int out_size, void* d_ws, size_t ws_size,
                              hipStream_t stream) {
    const float* x = (const float*)d_in[0];   // [8,256,16] f32
    const float* w = (const float*)d_in[1];   // [11] f32
    float* out = (float*)d_out;               // [8,256,11] f32

    qru_kernel<<<512, 256, 0, stream>>>(x, w, out);
}